// Round 1
// baseline (551.206 us; speedup 1.0000x reference)
//
#include <hip/hip_runtime.h>
#include <math.h>

#define CC 512
#define K1 25088      // 7*7*512
#define N1 512
#define NE 25690112   // 32*512*8*196 elements per output tensor

typedef unsigned short ushort_t;
typedef __attribute__((ext_vector_type(8))) short bf16x8;
typedef __attribute__((ext_vector_type(4))) float f32x4;
typedef __attribute__((address_space(3))) void* as3_void;
typedef const __attribute__((address_space(1))) void* as1_cvoid;

struct us4 { ushort_t a, b, c, d; };

__device__ __forceinline__ ushort_t f2bf(float f) {
  union { float f; unsigned u; } v; v.f = f;
  unsigned r = v.u + 0x7fffu + ((v.u >> 16) & 1u);
  return (ushort_t)(r >> 16);
}

__device__ __forceinline__ float gelu(float x) {
  return 0.5f * x * (1.0f + erff(x * 0.70710678118654752f));
}

// ---- merged stage: blocks [0,3136) transpose W1 -> W1t bf16; blocks
// [3136,7232) pool 14x14->7x7 + bf16 cast. Independent work, one launch
// so the two streams overlap instead of serializing.
__global__ __launch_bounds__(256)
void k_stage(const float* __restrict__ x, const float* __restrict__ W1,
             ushort_t* __restrict__ A, ushort_t* __restrict__ W1t) {
  __shared__ __align__(16) float smem[64 * 197];   // 50,432 B, shared by both roles
  int tid = threadIdx.x;
  if (blockIdx.x < 3136) {
    // W1 (25088 x 512 fp32 [k][n]) -> W1t bf16 [n][k], 64x64 tiles
    float (*tile)[65] = (float (*)[65])smem;
    int u = blockIdx.x;
    int k0 = (u % 392) * 64;
    int n0 = (u / 392) * 64;
    int rg = tid >> 4;        // 0..15
    int m  = tid & 15;        // 0..15
    for (int it = 0; it < 4; ++it) {
      int row = rg + it * 16;                       // k within tile
      float4 v = *(const float4*)&W1[(size_t)(k0 + row) * N1 + n0 + m * 4];
      tile[row][m * 4 + 0] = v.x;
      tile[row][m * 4 + 1] = v.y;
      tile[row][m * 4 + 2] = v.z;
      tile[row][m * 4 + 3] = v.w;
    }
    __syncthreads();
    for (int it = 0; it < 4; ++it) {
      int n = rg + it * 16;                         // n within tile
      int kb = m * 4;
      us4 o;
      o.a = f2bf(tile[kb + 0][n]);
      o.b = f2bf(tile[kb + 1][n]);
      o.c = f2bf(tile[kb + 2][n]);
      o.d = f2bf(tile[kb + 3][n]);
      *(us4*)&W1t[(size_t)(n0 + n) * K1 + k0 + kb] = o;
    }
  } else {
    // pool: A[bt][(i*7+j)*512+c]
    float (*s)[197] = (float (*)[197])smem;
    int bx = blockIdx.x - 3136;
    int cch = bx & 7;
    int t = (bx >> 3) & 15;
    int b = bx >> 7;
    int c0 = cch * 64;
    for (int idx = tid; idx < 3136; idx += 256) {
      int c = idx / 49;
      int q = idx - c * 49;
      float4 v = *(const float4*)&x[(((size_t)(b * 512 + c0 + c) * 16) + t) * 196 + q * 4];
      s[c][q * 4 + 0] = v.x;
      s[c][q * 4 + 1] = v.y;
      s[c][q * 4 + 2] = v.z;
      s[c][q * 4 + 3] = v.w;
    }
    __syncthreads();
    ushort_t* dst = A + (size_t)(b * 16 + t) * K1 + c0;
    for (int o = tid; o < 3136; o += 256) {
      int ij = o >> 6;          // 0..48
      int c = o & 63;
      int i = ij / 7;
      int j = ij - i * 7;
      int pos = i * 28 + j * 2; // (2i)*14 + 2j
      float v = (s[c][pos] + s[c][pos + 1] + s[c][pos + 14] + s[c][pos + 15]) * 0.25f;
      dst[ij * 512 + c] = f2bf(v);
    }
  }
}

// ---- GEMM1: Cp[z][512][512] = A[512xK1] * W1t^T (bf16 MFMA, split-K 49) ----
__global__ __launch_bounds__(256)
void k_gemm1(const ushort_t* __restrict__ A, const ushort_t* __restrict__ Bt,
             float* __restrict__ Cp) {
  __shared__ __align__(16) short As[4][128][8];
  __shared__ __align__(16) short Bs[4][128][8];
  int row0 = blockIdx.x * 128;
  int col0 = blockIdx.y * 128;
  int k0 = blockIdx.z * 512;
  int lane = threadIdx.x & 63;
  int wave = threadIdx.x >> 6;
  int wm = (wave & 1) * 64;
  int wn = (wave >> 1) * 64;
  f32x4 acc[4][4] = {};

  for (int kk = 0; kk < 512; kk += 32) {
    __syncthreads();
    for (int t = 0; t < 2; ++t) {
      int wt = wave * 2 + t;
      int ch = wt >> 1;            // chunk plane 0..3
      int r0 = (wt & 1) * 64;      // wave-uniform row base
      int rr = r0 + lane;
      const ushort_t* ga = A  + (size_t)(row0 + rr) * K1 + (k0 + kk + ch * 8);
      const ushort_t* gb = Bt + (size_t)(col0 + rr) * K1 + (k0 + kk + ch * 8);
      __builtin_amdgcn_global_load_lds((as1_cvoid)ga, (as3_void)&As[ch][r0][0], 16, 0, 0);
      __builtin_amdgcn_global_load_lds((as1_cvoid)gb, (as3_void)&Bs[ch][r0][0], 16, 0, 0);
    }
    __syncthreads();
    int ml = lane & 15, q = lane >> 4;
    bf16x8 af[4], bfr[4];
    for (int sm = 0; sm < 4; ++sm)
      af[sm] = *(const bf16x8*)&As[q][wm + sm * 16 + ml][0];
    for (int sn = 0; sn < 4; ++sn)
      bfr[sn] = *(const bf16x8*)&Bs[q][wn + sn * 16 + ml][0];
    for (int sm = 0; sm < 4; ++sm)
      for (int sn = 0; sn < 4; ++sn)
        acc[sm][sn] = __builtin_amdgcn_mfma_f32_16x16x32_bf16(af[sm], bfr[sn], acc[sm][sn], 0, 0, 0);
  }
  int ml = lane & 15, q = lane >> 4;
  float* out = Cp + (size_t)blockIdx.z * 262144;
  for (int sm = 0; sm < 4; ++sm)
    for (int sn = 0; sn < 4; ++sn)
      for (int rg = 0; rg < 4; ++rg) {
        int row = row0 + wm + sm * 16 + q * 4 + rg;
        int col = col0 + wn + sn * 16 + ml;
        out[row * N1 + col] = acc[sm][sn][rg];
      }
}

// ---- reduce 49 split-K partials + bias + exact GELU (float4) ----
__global__ __launch_bounds__(256)
void k_reduce(const float* __restrict__ Cp, const float* __restrict__ b1,
              float* __restrict__ h) {
  int i4 = blockIdx.x * 256 + threadIdx.x;   // 65536 float4s
  const float4* cp4 = (const float4*)Cp;
  float4 a = cp4[i4];
  for (int z = 1; z < 49; ++z) {
    float4 v = cp4[(size_t)z * 65536 + i4];
    a.x += v.x; a.y += v.y; a.z += v.z; a.w += v.w;
  }
  float4 bb = ((const float4*)b1)[i4 & 127];
  float4 r;
  r.x = gelu(a.x + bb.x);
  r.y = gelu(a.y + bb.y);
  r.z = gelu(a.z + bb.z);
  r.w = gelu(a.w + bb.w);
  ((float4*)h)[i4] = r;
}

// ---- fused head: feat = h @ W2 + b2, attn softmax, tanh offsets ----
// 512 threads (8 waves) per batch; softmax + offset dots wave-parallel.
__global__ __launch_bounds__(512)
void k_head(const float* __restrict__ h, const float* __restrict__ W2,
            const float* __restrict__ b2, const float* __restrict__ Wa,
            const float* __restrict__ Wd, float* __restrict__ offs) {
  int b = blockIdx.x;
  __shared__ float hs[16][512];   // 32KB
  __shared__ float fl[16][65];    // feat, padded
  __shared__ float lg[256];       // softmax probs
  __shared__ float pr[16][17];    // offset partials
  int tid = threadIdx.x;
  // load h row-block: 2048 float4 over 512 threads
  {
    const float4* src = (const float4*)(h + (size_t)b * 8192);
    float4* dst = (float4*)&hs[0][0];
    for (int i = tid; i < 2048; i += 512) dst[i] = src[i];
  }
  __syncthreads();
  // feat = h @ W2 + b2 : 16x64 outputs, K=512. 8 waves, 2 rows/thread.
  {
    int n = tid & 63;
    int tg = tid >> 6;            // wave index 0..7 -> rows tg, tg+8
    float acc0 = 0.f, acc1 = 0.f;
    #pragma unroll 4
    for (int k = 0; k < 512; ++k) {
      float w = W2[k * 64 + n];
      acc0 += hs[tg][k] * w;
      acc1 += hs[tg + 8][k] * w;
    }
    float bias = b2[n];
    fl[tg][n] = acc0 + bias;
    fl[tg + 8][n] = acc1 + bias;
  }
  __syncthreads();
  // logits + row softmax, wave-parallel: thread (t= tid>>4, s= tid&15),
  // row lives in a 16-lane group -> shfl_xor reductions.
  if (tid < 256) {
    int t = tid >> 4, s = tid & 15;
    float a = 0.f;
    for (int d = 0; d < 64; ++d) a += fl[t][d] * fl[s][d];
    a *= (1.0f / 512.0f);
    float m = a;
    for (int w = 1; w < 16; w <<= 1) m = fmaxf(m, __shfl_xor(m, w, 16));
    float e = expf(a - m);
    float sum = e;
    for (int w = 1; w < 16; w <<= 1) sum += __shfl_xor(sum, w, 16);
    lg[tid] = e / sum;
  }
  __syncthreads();
  // offsets: 16 outputs x 256-dot, chunked over 256 threads (16 f's each)
  if (tid < 256) {
    int o = tid & 15;             // output slot: 0..7 = Wa, 8..15 = Wd
    int ch = tid >> 4;            // chunk 0..15
    const float* W = (o >= 8) ? Wd : Wa;
    int col = o & 7;
    float a = 0.f;
    int f0 = ch * 16;
    for (int f = f0; f < f0 + 16; ++f) a += lg[f] * W[f * 8 + col];
    pr[ch][o] = a;
  }
  __syncthreads();
  if (tid < 16) {
    float a = 0.f;
    for (int ch = 0; ch < 16; ++ch) a += pr[ch][tid];
    offs[b * 16 + tid] = tanhf(a) * 2.0f;
  }
}

// ---- temporal bilinear sample: one block per (b,c), slice staged once ----
__global__ __launch_bounds__(256)
void k_sample(const float* __restrict__ x, const float* __restrict__ offs,
              float* __restrict__ out) {
  int bc = blockIdx.x;        // b*512 + c
  int b = bc >> 9;
  __shared__ float4 xs[16 * 49];   // 16 t-slices x 196 floats
  __shared__ int i0s[16], i1s[16];
  __shared__ float wfr[16];
  int tid = threadIdx.x;
  const float4* src = (const float4*)(x + (size_t)bc * 16 * 196);
  for (int i = tid; i < 784; i += 256) xs[i] = src[i];
  if (tid < 16) {
    int which = tid >> 3, to = tid & 7;
    float idx = (float)(2 * to + which) + offs[b * 16 + tid];
    float p = idx * (16.0f / 15.0f) - 0.5f;
    float fl = floorf(p);
    int i0 = (int)fl;
    wfr[tid] = p - fl;
    i0s[tid] = min(max(i0, 0), 15);
    i1s[tid] = min(max(i0 + 1, 0), 15);
  }
  __syncthreads();
  float4* out4 = (float4*)out;
  for (int oi = tid; oi < 784; oi += 256) {
    int which = oi / 392;
    int rem = oi - which * 392;
    int to = rem / 49;
    int q = rem - to * 49;
    int slot = which * 8 + to;
    float w = wfr[slot];
    float4 g0 = xs[i0s[slot] * 49 + q];
    float4 g1 = xs[i1s[slot] * 49 + q];
    float4 o;
    o.x = g0.x + w * (g1.x - g0.x);
    o.y = g0.y + w * (g1.y - g0.y);
    o.z = g0.z + w * (g1.z - g0.z);
    o.w = g0.w + w * (g1.w - g0.w);
    out4[(size_t)which * (NE / 4) + (size_t)(bc * 8 + to) * 49 + q] = o;
  }
}

extern "C" void kernel_launch(void* const* d_in, const int* in_sizes, int n_in,
                              void* d_out, int out_size, void* d_ws, size_t ws_size,
                              hipStream_t stream) {
  const float* x  = (const float*)d_in[0];
  const float* W1 = (const float*)d_in[1];
  const float* b1 = (const float*)d_in[2];
  const float* W2 = (const float*)d_in[3];
  const float* b2 = (const float*)d_in[4];
  const float* Wa = (const float*)d_in[5];
  const float* Wd = (const float*)d_in[6];
  float* out = (float*)d_out;

  char* w = (char*)d_ws;
  ushort_t* Abf  = (ushort_t*)(w);                 // 25,690,112 B
  ushort_t* W1t  = (ushort_t*)(w + 25690112);      // 25,690,112 B
  float*    Cp   = (float*)(w + 51380224);         // 49 MB partials
  float*    h    = (float*)(w + 51380224 + 51380224);  // 1 MB
  float*    offs = (float*)(w + 51380224 + 51380224 + 1048576);

  k_stage<<<7232, 256, 0, stream>>>(x, W1, Abf, W1t);
  k_gemm1<<<dim3(4, 4, 49), 256, 0, stream>>>(Abf, W1t, Cp);
  k_reduce<<<256, 256, 0, stream>>>(Cp, b1, h);
  k_head<<<32, 512, 0, stream>>>(h, W2, b2, Wa, Wd, offs);
  k_sample<<<16384, 256, 0, stream>>>(x, offs, out);
}